// Round 2
// baseline (10.531 us; speedup 1.0000x reference)
//
#include <hip/hip_runtime.h>

// SSD PriorBox generation — branchless decode version.
// 6 layers, shapes (lw,lh) in d_in[4] (int32 pairs), K = 2+len(ars) boxes/cell.
// AR_SEL = {0,1,1,1,0,0}: layers 0,4,5 use ar2 (K=4), layers 1,2,3 use ar4 (K=6).
// Total boxes = 8732; out = 8732 x 4 fp32 (xmin,ymin,xmax,ymax).
// Box order: layer-major, cell row-major, then k (min, geo, ars...).

__global__ __launch_bounds__(256) void prior_box_kernel(
        const float* __restrict__ min_sizes,
        const float* __restrict__ max_sizes,
        const float* __restrict__ ar2,
        const float* __restrict__ ar4,
        const int*   __restrict__ shapes,
        float*       __restrict__ out,
        int n_boxes) {
    int idx = blockIdx.x * blockDim.x + threadIdx.x;
    if (idx >= n_boxes) return;

    // Load all 12 shape ints in 3 wide loads (issued in parallel, no branches).
    int4 s0 = reinterpret_cast<const int4*>(shapes)[0];  // lw0 lh0 lw1 lh1
    int4 s1 = reinterpret_cast<const int4*>(shapes)[1];  // lw2 lh2 lw3 lh3
    int4 s2 = reinterpret_cast<const int4*>(shapes)[2];  // lw4 lh4 lw5 lh5

    int lws[6] = {s0.x, s0.z, s1.x, s1.z, s2.x, s2.z};
    int lhs[6] = {s0.y, s0.w, s1.y, s1.w, s2.y, s2.w};
    const int Ks[6] = {4, 6, 6, 6, 4, 4};     // 2 + len(ars), AR_SEL constant

    // Branchless layer select: prefix sums of per-layer box counts.
    int cnt0 = lws[0] * lhs[0] * Ks[0];
    int cnt1 = lws[1] * lhs[1] * Ks[1];
    int cnt2 = lws[2] * lhs[2] * Ks[2];
    int cnt3 = lws[3] * lhs[3] * Ks[3];
    int cnt4 = lws[4] * lhs[4] * Ks[4];
    int p1 = cnt0;
    int p2 = p1 + cnt1;
    int p3 = p2 + cnt2;
    int p4 = p3 + cnt3;
    int p5 = p4 + cnt4;
    int L = (idx >= p1) + (idx >= p2) + (idx >= p3) + (idx >= p4) + (idx >= p5);
    int base = 0;
    base = (L > 0) ? p1 : base;
    base = (L > 1) ? p2 : base;
    base = (L > 2) ? p3 : base;
    base = (L > 3) ? p4 : base;
    base = (L > 4) ? p5 : base;
    int rem = idx - base;

    int lw = lws[L];
    int lh = lhs[L];
    bool k6 = (L >= 1 && L <= 3);

    int cell, k;
    if (k6) { cell = rem / 6; k = rem - cell * 6; }     // magic-mul div by 6
    else    { cell = rem >> 2; k = rem & 3; }
    int i = cell / lw;                                  // lw <= 38
    int j = cell - i * lw;

    // Reference: cx = (j+0.5)*(IMG_W/lh); cy = (i+0.5)*(IMG_H/lw)  (crossed divisors)
    float cx = ((float)j + 0.5f) * (300.0f / (float)lh);
    float cy = ((float)i + 0.5f) * (300.0f / (float)lw);

    float ms = min_sizes[L];
    float w, h;
    if (k == 0) {
        w = ms; h = ms;
    } else if (k == 1) {
        float g = sqrtf(ms * max_sizes[L]);
        w = g; h = g;
    } else {
        const float* ars = k6 ? ar4 : ar2;
        float a  = ars[k - 2];
        float sa = sqrtf(a);
        w = ms * sa;
        h = ms / sa;
    }

    const float inv = 1.0f / 300.0f;
    float x0 = (cx - 0.5f * w) * inv;
    float y0 = (cy - 0.5f * h) * inv;
    float x1 = (cx + 0.5f * w) * inv;
    float y1 = (cy + 0.5f * h) * inv;

    x0 = fminf(fmaxf(x0, 0.0f), 1.0f);
    y0 = fminf(fmaxf(y0, 0.0f), 1.0f);
    x1 = fminf(fmaxf(x1, 0.0f), 1.0f);
    y1 = fminf(fmaxf(y1, 0.0f), 1.0f);

    reinterpret_cast<float4*>(out)[idx] = make_float4(x0, y0, x1, y1);
}

extern "C" void kernel_launch(void* const* d_in, const int* in_sizes, int n_in,
                              void* d_out, int out_size, void* d_ws, size_t ws_size,
                              hipStream_t stream) {
    const float* min_sizes = (const float*)d_in[0];
    const float* max_sizes = (const float*)d_in[1];
    const float* ar2       = (const float*)d_in[2];
    const float* ar4       = (const float*)d_in[3];
    const int*   shapes    = (const int*)d_in[4];
    float* out = (float*)d_out;

    int n_boxes = out_size / 4;        // 8732
    int block = 256;
    int grid = (n_boxes + block - 1) / block;
    prior_box_kernel<<<grid, block, 0, stream>>>(min_sizes, max_sizes, ar2, ar4,
                                                 shapes, out, n_boxes);
}